// Round 5
// baseline (611.613 us; speedup 1.0000x reference)
//
#include <hip/hip_runtime.h>

// WeatherLSTM on MI355X — round 5: pair-split N, fully register-resident B.
// 256 wgs x 512 threads = 128 pairs; pair P owns batch rows P*16..P*16+15.
// Each wg computes gates for its 128 h-cols (N=384: {i,o,g}x128), K=288
// (256 h + 8 x + bias-1.0 slot + zero pad). 27 MFMAs/wave, B entirely in
// registers (108 VGPRs) -> no LDS-B, no L2 weight stream. Per step the pair
// exchanges 4KB h-halves via agent-scope atomics (relaxed u64 data +
// exact-match monotonic flag, parity double-buffered; flags zeroed per
// launch by init kernel). Pairs co-XCD via wg^8 partnering heuristic.
// Dynamic LDS pads to >80KB to force 1 wg/CU.

typedef short bf16x8 __attribute__((ext_vector_type(8)));
typedef float f32x4 __attribute__((ext_vector_type(4)));

#define T_ENC 256
#define N_DEC 23
#define NSTEP 279
#define HSTR 296                       // h row stride in shorts (592 B)
#define X_OFF 458752                   // after Wpack (442368 B), 16KB-aligned
#define FLAG_OFF (X_OFF + 128 * 2 * 2 * 4096)  // X: pair x slot x eta x 4KB

__device__ __forceinline__ short f2bf(float f) {
  unsigned u = __float_as_uint(f);
  u = (u + 0x7fffu + ((u >> 16) & 1u)) >> 16;  // RNE
  return (short)u;
}
__device__ __forceinline__ float bf2f(short s) {
  return __uint_as_float(((unsigned)(unsigned short)s) << 16);
}

#if __has_builtin(__builtin_amdgcn_rcpf)
#define RCPF(x) __builtin_amdgcn_rcpf(x)
#else
#define RCPF(x) (1.0f / (x))
#endif

__device__ __forceinline__ float sigm(float x) { return RCPF(1.0f + __expf(-x)); }
__device__ __forceinline__ float tanhf_fast(float x) {
  return 1.0f - 2.0f * RCPF(__expf(2.0f * x) + 1.0f);
}

// Pack [Wh;Wx;bias;0] (3 gates i|o|g) into B-frag layout, n_tile = (eta*8+w)*3+t.
__global__ void pack_kernel(const float* __restrict__ Wx, const float* __restrict__ Wh,
                            const float* __restrict__ b, short* __restrict__ Wpack) {
  int tau = blockIdx.x;  // 0..431 = n_tile*9 + kt
  int l = threadIdx.x;
  int n_tile = tau / 9, kt = tau % 9;
  int eta = n_tile / 24, rem = n_tile % 24;
  int w = rem / 3, t = rem % 3;
  int base = (t == 0) ? 0 : (t == 1 ? 512 : 768);  // orig [i|f|o|c], f dropped
  int c = l & 15, q = l >> 4;
  int oc = base + eta * 128 + w * 16 + c;
  bf16x8 v;
#pragma unroll
  for (int e = 0; e < 8; ++e) {
    int k = kt * 32 + q * 8 + e;
    float f;
    if (k < 256)       f = Wh[k * 1024 + oc];
    else if (k < 264)  f = Wx[(k - 256) * 1024 + oc];
    else if (k == 264) f = b[oc];
    else               f = 0.0f;
    v[e] = f2bf(f);
  }
  ((bf16x8*)Wpack)[tau * 64 + l] = v;
}

__global__ void init_flags(unsigned* __restrict__ flags) {
  int i = blockIdx.x * 256 + threadIdx.x;
  if (i < 4096) flags[i] = 0u;
}

__global__ __launch_bounds__(512, 2) void lstm_kernel(
    const float* __restrict__ inputs0, const float* __restrict__ inputs1,
    const float* __restrict__ Wy, const float* __restrict__ by,
    const float* __restrict__ dec_w, const float* __restrict__ dec_b,
    const short* __restrict__ Wpack, unsigned long long* __restrict__ Xall,
    unsigned* __restrict__ flags, float* __restrict__ out) {
  __shared__ __align__(16) short hbuf[2][16 * HSTR];  // 18944 B double-buffered
  __shared__ float Wy_lds[256];
  __shared__ float ypart[256];
  extern __shared__ char lds_pad[];  // dynamic 65536 B -> forces 1 wg/CU

  const int tid = threadIdx.x;
  const int wg = blockIdx.x;                 // 0..255
  const int eta = (wg >> 3) & 1;             // half id
  const int etap = eta ^ 1;
  const int P = ((wg >> 4) << 3) | (wg & 7); // pair id 0..127 (co-XCD partner = wg^8)
  const int lane = tid & 63;
  const int w = tid >> 6;                    // wave 0..7
  const int q = lane >> 4;
  const int c = lane & 15;

  const bf16x8* wp = (const bf16x8*)Wpack;

  // ---- B fully register-resident: 27 tiles (3 gates x 9 kt) ----
  bf16x8 Breg[27];
#pragma unroll
  for (int r = 0; r < 27; ++r)
    Breg[r] = wp[((eta * 8 + w) * 27 + r) * 64 + lane];

  // flags/X pointers
  unsigned* flagOwn = flags + (P * 2 + eta) * 16;   // [slot 0..1], 64B per (P,eta)
  unsigned* flagPar = flags + (P * 2 + etap) * 16;

  // zero both h buffers (h cols, x region, bias+pad tail)
  for (int i = tid; i < 2 * 16 * HSTR; i += 512) hbuf[0][i] = 0;
  if (tid < 256) Wy_lds[tid] = Wy[tid];
  __syncthreads();
  if (tid < 128) {  // stage x(step 0) rows 0..15
    int m = tid >> 3, kk = tid & 7;
    hbuf[0][m * HSTR + 256 + kk] = f2bf(inputs0[((P * 16 + m) * 256 + 0) * 8 + kk]);
  }
  if (tid < 32) hbuf[tid >> 4][(tid & 15) * HSTR + 264] = (short)0x3F80;  // 1.0 bias slot
  const float byv = by[0];
  const int hcol = eta * 128 + w * 16 + c;
  __syncthreads();

  for (int s = 0; s < NSTEP; ++s) {
    const int cur = s & 1, nxt = cur ^ 1;
    const short* hc = &hbuf[cur][0];
    short* hn = &hbuf[nxt][0];

    // x prefetch for s+1 (global load overlaps MFMA)
    float xv = 0.0f;
    const bool do_x = (tid < 128) && (s + 1 < NSTEP);
    const int xm = tid >> 3, xk = tid & 7;
    if (do_x) {
      int sn = s + 1;
      if (sn < T_ENC) {
        xv = inputs0[((P * 16 + xm) * 256 + sn) * 8 + xk];
      } else {
        int d = sn - T_ENC;
        xv = inputs1[(P * 16 + xm) * N_DEC + d] * dec_w[d * 8 + xk] + dec_b[d * 8 + xk];
      }
    }

    // A-fragments (full 16 rows), then 27 MFMAs (B all in regs)
    bf16x8 A[9];
#pragma unroll
    for (int kt = 0; kt < 9; ++kt)
      A[kt] = *(const bf16x8*)(hc + c * HSTR + kt * 32 + q * 8);

    f32x4 acc[3];
#pragma unroll
    for (int t = 0; t < 3; ++t) { acc[t][0] = 0.f; acc[t][1] = 0.f; acc[t][2] = 0.f; acc[t][3] = 0.f; }
    __builtin_amdgcn_s_setprio(1);
#pragma unroll
    for (int kt = 0; kt < 9; ++kt) {
#pragma unroll
      for (int t = 0; t < 3; ++t)
        acc[t] = __builtin_amdgcn_mfma_f32_16x16x32_bf16(A[kt], Breg[t * 9 + kt], acc[t], 0, 0, 0);
    }
    __builtin_amdgcn_s_setprio(0);

    // activations: lane -> rows 4q..4q+3, col hcol (all 64 lanes useful)
    short hb[4];
#pragma unroll
    for (int r = 0; r < 4; ++r) {
      float ii = sigm(acc[0][r]);
      float oo = sigm(acc[1][r]);
      float gg = tanhf_fast(acc[2][r]);
      hb[r] = f2bf(oo * tanhf_fast(ii * gg));
      hn[(4 * q + r) * HSTR + hcol] = hb[r];
    }
    // own half -> exchange buffer (col-major u64: [col][rowgroup])
    unsigned long long pk =
        (unsigned long long)(unsigned short)hb[0] |
        ((unsigned long long)(unsigned short)hb[1] << 16) |
        ((unsigned long long)(unsigned short)hb[2] << 32) |
        ((unsigned long long)(unsigned short)hb[3] << 48);
    unsigned long long* Xown = Xall + ((unsigned)(P * 2 + nxt) * 2 + eta) * 512;
    __hip_atomic_store(&Xown[(w * 16 + c) * 4 + q], pk,
                       __ATOMIC_RELAXED, __HIP_MEMORY_SCOPE_AGENT);
    if (do_x) hn[xm * HSTR + 256 + xk] = f2bf(xv);
    __syncthreads();  // B1: all own stores acked (vmcnt drained per wave)

    if (tid == 0)
      __hip_atomic_store(&flagOwn[nxt], (unsigned)(s + 1),
                         __ATOMIC_RELAXED, __HIP_MEMORY_SCOPE_AGENT);
    // all-thread exact-match poll (partner at most 1 step ahead -> other slot)
    {
      const unsigned want = (unsigned)(s + 1);
      unsigned v = __hip_atomic_load(&flagPar[nxt], __ATOMIC_RELAXED, __HIP_MEMORY_SCOPE_AGENT);
      while (v != want) {
        __builtin_amdgcn_s_sleep(2);
        v = __hip_atomic_load(&flagPar[nxt], __ATOMIC_RELAXED, __HIP_MEMORY_SCOPE_AGENT);
      }
    }
    // stage partner half: thread t -> col t>>2, rowgroup t&3
    {
      unsigned long long* Xpar = Xall + ((unsigned)(P * 2 + nxt) * 2 + etap) * 512;
      unsigned long long pk2 = __hip_atomic_load(&Xpar[tid], __ATOMIC_RELAXED, __HIP_MEMORY_SCOPE_AGENT);
      int col = tid >> 2, rg = tid & 3;
      int pcol = etap * 128 + col;
#pragma unroll
      for (int j = 0; j < 4; ++j)
        hn[(4 * rg + j) * HSTR + pcol] = (short)(pk2 >> (16 * j));
    }
    __syncthreads();  // B2: h(s+1) complete in LDS

    // y = h @ Wy + by (eta=0 wg only; encoder end + decoder steps)
    if (eta == 0 && s >= T_ENC - 1) {
      if (tid < 256) {
        int m = tid & 15, kq = tid >> 4;
        const short* hp = hn + m * HSTR + kq * 16;
        bf16x8 h0 = *(const bf16x8*)(hp);
        bf16x8 h1 = *(const bf16x8*)(hp + 8);
        float part = 0.0f;
#pragma unroll
        for (int j = 0; j < 8; ++j) {
          part += bf2f(h0[j]) * Wy_lds[kq * 16 + j];
          part += bf2f(h1[j]) * Wy_lds[kq * 16 + 8 + j];
        }
        ypart[tid] = part;
      }
      __syncthreads();
      if (tid < 16) {
        float y = byv;
#pragma unroll
        for (int kq = 0; kq < 16; ++kq) y += ypart[kq * 16 + tid];
        out[(P * 16 + tid) * 24 + (s - (T_ENC - 1))] = y;
      }
      // ypart reuse protected by next step's B1
    }
  }
}

extern "C" void kernel_launch(void* const* d_in, const int* in_sizes, int n_in,
                              void* d_out, int out_size, void* d_ws, size_t ws_size,
                              hipStream_t stream) {
  const float* inputs0 = (const float*)d_in[0];
  const float* inputs1 = (const float*)d_in[1];
  const float* Wx      = (const float*)d_in[2];
  const float* Wh      = (const float*)d_in[3];
  const float* b       = (const float*)d_in[4];
  const float* Wy      = (const float*)d_in[5];
  const float* by      = (const float*)d_in[6];
  const float* dec_w   = (const float*)d_in[7];
  const float* dec_b   = (const float*)d_in[8];

  short* Wpack = (short*)d_ws;
  unsigned long long* Xall = (unsigned long long*)((char*)d_ws + X_OFF);
  unsigned* flags = (unsigned*)((char*)d_ws + FLAG_OFF);

  pack_kernel<<<dim3(432), dim3(64), 0, stream>>>(Wx, Wh, b, Wpack);
  init_flags<<<dim3(16), dim3(256), 0, stream>>>(flags);
  lstm_kernel<<<dim3(256), dim3(512), 65536, stream>>>(
      inputs0, inputs1, Wy, by, dec_w, dec_b, Wpack, Xall, flags, (float*)d_out);
}

// Round 8
// 447.041 us; speedup vs baseline: 1.3681x; 1.3681x over previous
//
#include <hip/hip_runtime.h>

// WeatherLSTM on MI355X — round 8: AGPR-born weights + builtin MFMAs.
// 256 wgs x 512 threads; each wg owns 8 batch rows for all 279 steps.
// Per step: M=16(8 used),N=768,K=288 bf16 MFMA; f-gate dropped; x folded
// as 9th K-tile; bias via constant-1.0 A slot; A-row duplication (c&7)
// lets all 64 lanes do activations (4 outputs/lane, no cross-lane ops).
// B residency: per wave, gates i,o (36 tiles, 144 regs) forced into AGPR
// CLASS by a tied empty-asm def (not rematerializable -> must stay live);
// all MFMAs are BUILTINS (compiler manages every hazard — fixes r6/r7 NaN:
// hand-written asm MFMAs lacked required VALU<->MFMA wait states).
// Gate g (18 tiles) in LDS (147KB). LDS 153.7KB -> exactly 1 wg/CU.

typedef short bf16x8 __attribute__((ext_vector_type(8)));
typedef float f32x4 __attribute__((ext_vector_type(4)));

#define T_ENC 256
#define N_DEC 23
#define NSTEP 279
#define HSTR 296           // h row stride in shorts (592 B)
#define AG_T 36            // B-tiles per wave born in AGPRs (t=0..3: i,o)
#define LDS_T 18           // B-tiles per wave in LDS (t=4,5: g)

__device__ __forceinline__ short f2bf(float f) {
  unsigned u = __float_as_uint(f);
  u = (u + 0x7fffu + ((u >> 16) & 1u)) >> 16;  // RNE
  return (short)u;
}
__device__ __forceinline__ float bf2f(short s) {
  return __uint_as_float(((unsigned)(unsigned short)s) << 16);
}

#if __has_builtin(__builtin_amdgcn_rcpf)
#define RCPF(x) __builtin_amdgcn_rcpf(x)
#else
#define RCPF(x) (1.0f / (x))
#endif

__device__ __forceinline__ float sigm(float x) { return RCPF(1.0f + __expf(-x)); }
__device__ __forceinline__ float tanhf_fast(float x) {
  return 1.0f - 2.0f * RCPF(__expf(2.0f * x) + 1.0f);
}

// Pack [Wh;Wx;bias;0] (3 gates i|o|g) into B-frag layout (identical to r4/r6).
__global__ void pack_kernel(const float* __restrict__ Wx, const float* __restrict__ Wh,
                            const float* __restrict__ b, short* __restrict__ Wpack) {
  int tau = blockIdx.x;  // 0..431 = n_tile*9 + kt
  int l = threadIdx.x;
  int n_tile = tau / 9, kt = tau % 9;
  int w = n_tile / 6, t = n_tile % 6;
  int gate = t >> 1, loc = t & 1;
  int base = (gate == 0) ? 0 : (gate == 1 ? 512 : 768);  // [i|f|o|c], f dropped
  int c = l & 15, q = l >> 4;
  int oc = base + w * 32 + loc * 16 + c;
  bf16x8 v;
#pragma unroll
  for (int e = 0; e < 8; ++e) {
    int k = kt * 32 + q * 8 + e;
    float f;
    if (k < 256)       f = Wh[k * 1024 + oc];
    else if (k < 264)  f = Wx[(k - 256) * 1024 + oc];
    else if (k == 264) f = b[oc];
    else               f = 0.0f;
    v[e] = f2bf(f);
  }
  ((bf16x8*)Wpack)[tau * 64 + l] = v;
}

__global__ __launch_bounds__(512, 2) void lstm_kernel(
    const float* __restrict__ inputs0, const float* __restrict__ inputs1,
    const float* __restrict__ Wy, const float* __restrict__ by,
    const float* __restrict__ dec_w, const float* __restrict__ dec_b,
    const short* __restrict__ Wpack, float* __restrict__ out) {
  __shared__ __align__(16) short B_lds[8 * LDS_T * 512];  // 147456 B
  __shared__ __align__(16) short hbuf[8 * HSTR];          // 4736 B (8 rows)
  __shared__ float Wy_lds[256];
  __shared__ float ypart[128];
  // total 153728 B -> exactly 1 wg/CU

  const int tid = threadIdx.x;
  const int wg = blockIdx.x;     // 0..255, batch rows wg*8 .. wg*8+7
  const int lane = tid & 63;
  const int w = tid >> 6;        // wave 0..7
  const int q = lane >> 4;       // 0..3
  const int c = lane & 15;

  const bf16x8* wp = (const bf16x8*)Wpack;

  // ---- AGPR-born weights: tiles r = t*9+kt, t=0..3 (i and o gates).
  // Tied empty asm pins the value to AGPR class; asm results can't be
  // rematerialized, so regalloc keeps all 144 regs live across the loop.
  // Builtin MFMAs bind AGPR SrcB directly (gfx950 AV operands).
  bf16x8 Bag[AG_T];
#pragma unroll
  for (int r = 0; r < AG_T; ++r) {
    bf16x8 t0 = wp[(w * 54 + r) * 64 + lane];
    asm("" : "=a"(Bag[r]) : "0"(t0));
  }
  // ---- LDS weights: tiles 36..53 (g gate, t=4,5) ----
#pragma unroll
  for (int j = 0; j < LDS_T; ++j) {
    bf16x8 v = wp[(w * 54 + AG_T + j) * 64 + lane];
    *(bf16x8*)(B_lds + (w * LDS_T + j) * 512 + lane * 8) = v;
  }

  for (int i = tid; i < 8 * HSTR; i += 512) hbuf[i] = 0;
  if (tid < 256) Wy_lds[tid] = Wy[tid];
  __syncthreads();  // zero-init complete before x0/bias staging

  if (tid < 64) {  // stage x(step 0)
    int m = tid >> 3, kk = tid & 7;
    hbuf[m * HSTR + 256 + kk] = f2bf(inputs0[((wg * 8 + m) * 256 + 0) * 8 + kk]);
  }
  if (tid < 8) hbuf[tid * HSTR + 264] = (short)0x3F80;  // constant 1.0 (bias slot)
  const float byv = by[0];
  __syncthreads();

  // A-frag read with row duplication: row = c&7 (D rows 8-15 = copies of 0-7)
#define RDA(kt) (*(const bf16x8*)(hbuf + (c & 7) * HSTR + (kt) * 32 + q * 8))
#define LDSB(j) (*(const bf16x8*)(B_lds + (w * LDS_T + (j)) * 512 + lane * 8))

  for (int s = 0; s < NSTEP; ++s) {
    // x prefetch for s+1 (global load overlaps MFMA; consumed after barrier)
    float xv = 0.0f;
    const bool do_x = (tid < 64) && (s + 1 < NSTEP);
    const int xm = tid >> 3, xk = tid & 7;
    if (do_x) {
      int sn = s + 1;
      if (sn < T_ENC) {
        xv = inputs0[((wg * 8 + xm) * 256 + sn) * 8 + xk];
      } else {
        int d = sn - T_ENC;
        xv = inputs1[(wg * 8 + xm) * N_DEC + d] * dec_w[d * 8 + xk] + dec_b[d * 8 + xk];
      }
    }

    // MFMA loop: 54 builtin MFMAs/wave; A through 3-deep rolling window
    bf16x8 A3[3];
    A3[0] = RDA(0); A3[1] = RDA(1); A3[2] = RDA(2);
    f32x4 acc[6];
#pragma unroll
    for (int t = 0; t < 6; ++t) { acc[t][0] = 0.f; acc[t][1] = 0.f; acc[t][2] = 0.f; acc[t][3] = 0.f; }
#pragma unroll
    for (int kt = 0; kt < 9; ++kt) {
      const bf16x8 a = A3[kt % 3];
      acc[0] = __builtin_amdgcn_mfma_f32_16x16x32_bf16(a, Bag[0 * 9 + kt], acc[0], 0, 0, 0);
      acc[1] = __builtin_amdgcn_mfma_f32_16x16x32_bf16(a, Bag[1 * 9 + kt], acc[1], 0, 0, 0);
      acc[2] = __builtin_amdgcn_mfma_f32_16x16x32_bf16(a, Bag[2 * 9 + kt], acc[2], 0, 0, 0);
      acc[3] = __builtin_amdgcn_mfma_f32_16x16x32_bf16(a, Bag[3 * 9 + kt], acc[3], 0, 0, 0);
      acc[4] = __builtin_amdgcn_mfma_f32_16x16x32_bf16(a, LDSB(kt), acc[4], 0, 0, 0);
      acc[5] = __builtin_amdgcn_mfma_f32_16x16x32_bf16(a, LDSB(9 + kt), acc[5], 0, 0, 0);
      if (kt + 3 < 9) A3[kt % 3] = RDA(kt + 3);
    }
    __syncthreads();  // all A-reads done; h(s) free to overwrite

    // lane-split activations: q<2 -> col half 0, q>=2 -> half 1 (valid via
    // A-row duplication). Compile-time reg indices only.
    const int qh = q >> 1;
    const f32x4 vi = qh ? acc[1] : acc[0];
    const f32x4 vo = qh ? acc[3] : acc[2];
    const f32x4 vg = qh ? acc[5] : acc[4];
    const int row0 = (q & 1) * 4;
    const int colw = w * 32 + qh * 16 + c;
#pragma unroll
    for (int j = 0; j < 4; ++j) {
      float ii = sigm(vi[j]);
      float oo = sigm(vo[j]);
      float gg = tanhf_fast(vg[j]);
      float h = oo * tanhf_fast(ii * gg);
      hbuf[(row0 + j) * HSTR + colw] = f2bf(h);
    }
    if (do_x) hbuf[xm * HSTR + 256 + xk] = f2bf(xv);
    __syncthreads();  // h(s+1) visible

    // y = h @ Wy + by at encoder end (col 0) and every decoder step
    if (s >= T_ENC - 1) {
      if (tid < 128) {
        int m = tid & 7, kq = tid >> 3;
        const short* hp = hbuf + m * HSTR + kq * 16;
        bf16x8 h0 = *(const bf16x8*)(hp);
        bf16x8 h1 = *(const bf16x8*)(hp + 8);
        float part = 0.0f;
#pragma unroll
        for (int j = 0; j < 8; ++j) {
          part += bf2f(h0[j]) * Wy_lds[kq * 16 + j];
          part += bf2f(h1[j]) * Wy_lds[kq * 16 + 8 + j];
        }
        ypart[tid] = part;  // tid = kq*8 + m
      }
      __syncthreads();
      if (tid < 8) {
        float y = byv;
#pragma unroll
        for (int kq = 0; kq < 16; ++kq) y += ypart[kq * 8 + tid];
        out[(wg * 8 + tid) * 24 + (s - (T_ENC - 1))] = y;
      }
      // ypart reuse protected by next step's first barrier
    }
  }
}

extern "C" void kernel_launch(void* const* d_in, const int* in_sizes, int n_in,
                              void* d_out, int out_size, void* d_ws, size_t ws_size,
                              hipStream_t stream) {
  const float* inputs0 = (const float*)d_in[0];
  const float* inputs1 = (const float*)d_in[1];
  const float* Wx      = (const float*)d_in[2];
  const float* Wh      = (const float*)d_in[3];
  const float* b       = (const float*)d_in[4];
  const float* Wy      = (const float*)d_in[5];
  const float* by      = (const float*)d_in[6];
  const float* dec_w   = (const float*)d_in[7];
  const float* dec_b   = (const float*)d_in[8];

  short* Wpack = (short*)d_ws;

  pack_kernel<<<dim3(432), dim3(64), 0, stream>>>(Wx, Wh, b, Wpack);
  lstm_kernel<<<dim3(256), dim3(512), 0, stream>>>(
      inputs0, inputs1, Wy, by, dec_w, dec_b, Wpack, (float*)d_out);
}

// Round 9
// 426.990 us; speedup vs baseline: 1.4324x; 1.0470x over previous
//
#include <hip/hip_runtime.h>

// WeatherLSTM on MI355X — round 9: r8 + 1-barrier/step + MFMA∥act overlap.
// 256 wgs x 512 threads; each wg owns 8 batch rows for all 279 steps.
// Per step: M=16(8 used),N=768,K=288 bf16 MFMA; f-gate dropped; x folded
// as 9th K-tile; bias via constant-1.0 A slot; A-row duplication (c&7).
// B residency (proven r8): 36 tiles/wave AGPR-born, 18 tiles/wave in LDS.
// NEW: h double-buffered -> ONE barrier/step (write goes to other buffer);
// MFMA phased in gate pairs {i}{o}{g} so sigmoid of gate t overlaps the
// MFMAs of gate t+1; h-store via v_cvt_pk_bf16_f32 (RNE, 2 f32/instr).

typedef short bf16x8 __attribute__((ext_vector_type(8)));
typedef float f32x4 __attribute__((ext_vector_type(4)));

#define T_ENC 256
#define N_DEC 23
#define NSTEP 279
#define HSTR 296           // h row stride in shorts (592 B)
#define AG_T 36            // B-tiles per wave born in AGPRs (t=0..3: i,o)
#define LDS_T 18           // B-tiles per wave in LDS (t=4,5: g)

__device__ __forceinline__ short f2bf(float f) {
  unsigned u = __float_as_uint(f);
  u = (u + 0x7fffu + ((u >> 16) & 1u)) >> 16;  // RNE
  return (short)u;
}
__device__ __forceinline__ float bf2f(short s) {
  return __uint_as_float(((unsigned)(unsigned short)s) << 16);
}

#if __has_builtin(__builtin_amdgcn_rcpf)
#define RCPF(x) __builtin_amdgcn_rcpf(x)
#else
#define RCPF(x) (1.0f / (x))
#endif

__device__ __forceinline__ float sigm(float x) { return RCPF(1.0f + __expf(-x)); }
__device__ __forceinline__ float tanhf_fast(float x) {
  return 1.0f - 2.0f * RCPF(__expf(2.0f * x) + 1.0f);
}

// Pack [Wh;Wx;bias;0] (3 gates i|o|g) into B-frag layout (identical to r4/r8).
__global__ void pack_kernel(const float* __restrict__ Wx, const float* __restrict__ Wh,
                            const float* __restrict__ b, short* __restrict__ Wpack) {
  int tau = blockIdx.x;  // 0..431 = n_tile*9 + kt
  int l = threadIdx.x;
  int n_tile = tau / 9, kt = tau % 9;
  int w = n_tile / 6, t = n_tile % 6;
  int gate = t >> 1, loc = t & 1;
  int base = (gate == 0) ? 0 : (gate == 1 ? 512 : 768);  // [i|f|o|c], f dropped
  int c = l & 15, q = l >> 4;
  int oc = base + w * 32 + loc * 16 + c;
  bf16x8 v;
#pragma unroll
  for (int e = 0; e < 8; ++e) {
    int k = kt * 32 + q * 8 + e;
    float f;
    if (k < 256)       f = Wh[k * 1024 + oc];
    else if (k < 264)  f = Wx[(k - 256) * 1024 + oc];
    else if (k == 264) f = b[oc];
    else               f = 0.0f;
    v[e] = f2bf(f);
  }
  ((bf16x8*)Wpack)[tau * 64 + l] = v;
}

__global__ __launch_bounds__(512, 2) void lstm_kernel(
    const float* __restrict__ inputs0, const float* __restrict__ inputs1,
    const float* __restrict__ Wy, const float* __restrict__ by,
    const float* __restrict__ dec_w, const float* __restrict__ dec_b,
    const short* __restrict__ Wpack, float* __restrict__ out) {
  __shared__ __align__(16) short B_lds[8 * LDS_T * 512];  // 147456 B
  __shared__ __align__(16) short hbuf[2][8 * HSTR];       // 9472 B, double-buffered
  __shared__ float Wy_lds[256];
  __shared__ float ypart[128];
  // total ~158 KB -> exactly 1 wg/CU

  const int tid = threadIdx.x;
  const int wg = blockIdx.x;     // 0..255, batch rows wg*8 .. wg*8+7
  const int lane = tid & 63;
  const int w = tid >> 6;        // wave 0..7
  const int q = lane >> 4;       // 0..3
  const int c = lane & 15;

  const bf16x8* wp = (const bf16x8*)Wpack;

  // ---- AGPR-born weights: tiles r = t*9+kt, t=0..3 (i and o gates) ----
  bf16x8 Bag[AG_T];
#pragma unroll
  for (int r = 0; r < AG_T; ++r) {
    bf16x8 t0 = wp[(w * 54 + r) * 64 + lane];
    asm("" : "=a"(Bag[r]) : "0"(t0));
  }
  // ---- LDS weights: tiles 36..53 (g gate, t=4,5) ----
#pragma unroll
  for (int j = 0; j < LDS_T; ++j) {
    bf16x8 v = wp[(w * 54 + AG_T + j) * 64 + lane];
    *(bf16x8*)(B_lds + (w * LDS_T + j) * 512 + lane * 8) = v;
  }

  for (int i = tid; i < 2 * 8 * HSTR; i += 512) hbuf[0][i] = 0;
  if (tid < 256) Wy_lds[tid] = Wy[tid];
  __syncthreads();  // zero-init complete before x0/bias staging

  if (tid < 64) {  // stage x(step 0) into buffer 0
    int m = tid >> 3, kk = tid & 7;
    hbuf[0][m * HSTR + 256 + kk] = f2bf(inputs0[((wg * 8 + m) * 256 + 0) * 8 + kk]);
  }
  if (tid < 16)  // constant 1.0 bias slot in BOTH buffers
    hbuf[tid >> 3][(tid & 7) * HSTR + 264] = (short)0x3F80;
  const float byv = by[0];
  __syncthreads();

  // A-frag read with row duplication: row = c&7 (D rows 8-15 = copies of 0-7)
#define LDSB(j) (*(const bf16x8*)(B_lds + (w * LDS_T + (j)) * 512 + lane * 8))

  const int qh = q >> 1;
  const int row0 = (q & 1) * 4;
  const int colw = w * 32 + qh * 16 + c;

  for (int s = 0; s < NSTEP; ++s) {
    const short* hc = &hbuf[s & 1][0];
    short* hn = &hbuf[(s + 1) & 1][0];

    // x prefetch for s+1 (global load issued early, overlaps MFMA)
    float xv = 0.0f;
    const bool do_x = (tid < 64) && (s + 1 < NSTEP);
    const int xm = tid >> 3, xk = tid & 7;
    if (do_x) {
      int sn = s + 1;
      if (sn < T_ENC) {
        xv = inputs0[((wg * 8 + xm) * 256 + sn) * 8 + xk];
      } else {
        int d = sn - T_ENC;
        xv = inputs1[(wg * 8 + xm) * N_DEC + d] * dec_w[d * 8 + xk] + dec_b[d * 8 + xk];
      }
    }

    // A-fragments upfront (9 x ds_read_b128)
    bf16x8 A[9];
#pragma unroll
    for (int kt = 0; kt < 9; ++kt)
      A[kt] = *(const bf16x8*)(hc + (c & 7) * HSTR + kt * 32 + q * 8);

    // ---- phase i (t=0,1): 18 MFMAs, then sigm(i) overlaps phase o ----
    f32x4 a0, a1;
    a0[0]=0.f;a0[1]=0.f;a0[2]=0.f;a0[3]=0.f; a1=a0;
#pragma unroll
    for (int kt = 0; kt < 9; ++kt) {
      a0 = __builtin_amdgcn_mfma_f32_16x16x32_bf16(A[kt], Bag[0 * 9 + kt], a0, 0, 0, 0);
      a1 = __builtin_amdgcn_mfma_f32_16x16x32_bf16(A[kt], Bag[1 * 9 + kt], a1, 0, 0, 0);
    }
    float ii[4];
    {
      const f32x4 vi = qh ? a1 : a0;
#pragma unroll
      for (int j = 0; j < 4; ++j) ii[j] = sigm(vi[j]);
    }
    // ---- phase o (t=2,3) ----
    a0[0]=0.f;a0[1]=0.f;a0[2]=0.f;a0[3]=0.f; a1=a0;
#pragma unroll
    for (int kt = 0; kt < 9; ++kt) {
      a0 = __builtin_amdgcn_mfma_f32_16x16x32_bf16(A[kt], Bag[2 * 9 + kt], a0, 0, 0, 0);
      a1 = __builtin_amdgcn_mfma_f32_16x16x32_bf16(A[kt], Bag[3 * 9 + kt], a1, 0, 0, 0);
    }
    float oo[4];
    {
      const f32x4 vo = qh ? a1 : a0;
#pragma unroll
      for (int j = 0; j < 4; ++j) oo[j] = sigm(vo[j]);
    }
    // ---- phase g (t=4,5, B from LDS) ----
    a0[0]=0.f;a0[1]=0.f;a0[2]=0.f;a0[3]=0.f; a1=a0;
#pragma unroll
    for (int kt = 0; kt < 9; ++kt) {
      a0 = __builtin_amdgcn_mfma_f32_16x16x32_bf16(A[kt], LDSB(kt), a0, 0, 0, 0);
      a1 = __builtin_amdgcn_mfma_f32_16x16x32_bf16(A[kt], LDSB(9 + kt), a1, 0, 0, 0);
    }
    float hh[4];
    {
      const f32x4 vg = qh ? a1 : a0;
#pragma unroll
      for (int j = 0; j < 4; ++j) {
        float gg = tanhf_fast(vg[j]);
        hh[j] = oo[j] * tanhf_fast(ii[j] * gg);
      }
    }
    // h-store: pack pairs with v_cvt_pk_bf16_f32 (RNE), write rows 4q..4q+3
    {
      unsigned pk01, pk23;
      asm("v_cvt_pk_bf16_f32 %0, %1, %2" : "=v"(pk01) : "v"(hh[0]), "v"(hh[1]));
      asm("v_cvt_pk_bf16_f32 %0, %1, %2" : "=v"(pk23) : "v"(hh[2]), "v"(hh[3]));
      hn[(row0 + 0) * HSTR + colw] = (short)(pk01 & 0xffffu);
      hn[(row0 + 1) * HSTR + colw] = (short)(pk01 >> 16);
      hn[(row0 + 2) * HSTR + colw] = (short)(pk23 & 0xffffu);
      hn[(row0 + 3) * HSTR + colw] = (short)(pk23 >> 16);
    }
    if (do_x) hn[xm * HSTR + 256 + xk] = f2bf(xv);
    __syncthreads();  // the ONLY per-step barrier: publish h(s+1)

    // y = h @ Wy + by at encoder end (col 0) and every decoder step
    if (s >= T_ENC - 1) {
      if (tid < 128) {
        int m = tid & 7, kq = tid >> 3;
        const short* hp = hn + m * HSTR + kq * 16;
        bf16x8 h0 = *(const bf16x8*)(hp);
        bf16x8 h1 = *(const bf16x8*)(hp + 8);
        float part = 0.0f;
#pragma unroll
        for (int j = 0; j < 8; ++j) {
          part += bf2f(h0[j]) * Wy_lds[kq * 16 + j];
          part += bf2f(h1[j]) * Wy_lds[kq * 16 + 8 + j];
        }
        ypart[tid] = part;  // tid = kq*8 + m
      }
      __syncthreads();
      if (tid < 8) {
        float y = byv;
#pragma unroll
        for (int kq = 0; kq < 16; ++kq) y += ypart[kq * 8 + tid];
        out[(wg * 8 + tid) * 24 + (s - (T_ENC - 1))] = y;
      }
      __syncthreads();  // ypart safe for next y-step; cheap (24 steps only)
    }
  }
}

extern "C" void kernel_launch(void* const* d_in, const int* in_sizes, int n_in,
                              void* d_out, int out_size, void* d_ws, size_t ws_size,
                              hipStream_t stream) {
  const float* inputs0 = (const float*)d_in[0];
  const float* inputs1 = (const float*)d_in[1];
  const float* Wx      = (const float*)d_in[2];
  const float* Wh      = (const float*)d_in[3];
  const float* b       = (const float*)d_in[4];
  const float* Wy      = (const float*)d_in[5];
  const float* by      = (const float*)d_in[6];
  const float* dec_w   = (const float*)d_in[7];
  const float* dec_b   = (const float*)d_in[8];

  short* Wpack = (short*)d_ws;

  pack_kernel<<<dim3(432), dim3(64), 0, stream>>>(Wx, Wh, b, Wpack);
  lstm_kernel<<<dim3(256), dim3(512), 0, stream>>>(
      inputs0, inputs1, Wy, by, dec_w, dec_b, Wpack, (float*)d_out);
}